// Round 1
// baseline (540.168 us; speedup 1.0000x reference)
//
#include <hip/hip_runtime.h>
#include <hip/hip_bf16.h>

#define N_NODES 50000
#define N_EDGES 312500
#define WIDTH   256
#define LN_EPS  1e-5f

// ---------------------------------------------------------------------------
// Degree kernels
// ---------------------------------------------------------------------------
__global__ void deg_init(float* __restrict__ deg, int n) {
    int i = blockIdx.x * blockDim.x + threadIdx.x;
    if (i < n) deg[i] = 1.0f;  // self-loop contributes 1
}

__global__ void deg_count(const int* __restrict__ dst, float* __restrict__ deg, int e) {
    int i = blockIdx.x * blockDim.x + threadIdx.x;
    if (i < e) atomicAdd(&deg[dst[i]], 1.0f);
}

__global__ void deg_rsqrt(float* __restrict__ deg, int n) {
    int i = blockIdx.x * blockDim.x + threadIdx.x;
    if (i < n) deg[i] = rsqrtf(deg[i]);  // deg >= 1 always (self-loop)
}

// ---------------------------------------------------------------------------
// GEMM: h[n][c] = sum_k x[n][k] * W[c][k]   (h = x @ W^T)
// block = 64 rows x 256 cols, thread = 16 rows x 4 cols, K chunked by 32.
// xs stored [k][r]: inner-loop reads are whole-wave broadcasts (free).
// ws stored [k][c]: b128 reads cover all 32 banks uniformly (no conflict).
// ---------------------------------------------------------------------------
#define KC 32
__global__ __launch_bounds__(256) void gemm_xWt(const float* __restrict__ x,
                                                const float* __restrict__ W,
                                                float* __restrict__ h, int n) {
    __shared__ float xs[KC][64];    // [k][r]
    __shared__ float wsm[KC][256];  // [k][c]
    const int t    = threadIdx.x;
    const int tx   = t & 63;        // column group: col0 = tx*4
    const int ty   = t >> 6;        // row group (== wave id): rows ty*16..+15
    const int col0 = tx * 4;
    const int row0g = blockIdx.x * 64;

    float acc[16][4];
    #pragma unroll
    for (int i = 0; i < 16; i++)
        #pragma unroll
        for (int j = 0; j < 4; j++) acc[i][j] = 0.0f;

    for (int k0 = 0; k0 < WIDTH; k0 += KC) {
        // ---- stage x chunk: 64 rows x KC k (2048 floats, 2 float4/thread)
        {
            int r  = t & 63;
            int kq = (t >> 6) * 8;          // each wave loads 8 consecutive k
            int gr = row0g + r;
            if (gr < n) {
                const float* xp = x + (size_t)gr * WIDTH + k0 + kq;
                float4 v0 = *(const float4*)xp;
                float4 v1 = *(const float4*)(xp + 4);
                xs[kq + 0][r] = v0.x; xs[kq + 1][r] = v0.y;
                xs[kq + 2][r] = v0.z; xs[kq + 3][r] = v0.w;
                xs[kq + 4][r] = v1.x; xs[kq + 5][r] = v1.y;
                xs[kq + 6][r] = v1.z; xs[kq + 7][r] = v1.w;
            } else {
                #pragma unroll
                for (int j = 0; j < 8; j++) xs[kq + j][r] = 0.0f;
            }
        }
        // ---- stage W chunk transposed: 256 c x KC k (8 float4/thread)
        {
            int c = t;
            const float* wp = W + (size_t)c * WIDTH + k0;
            #pragma unroll
            for (int q = 0; q < 8; q++) {
                float4 v = *(const float4*)(wp + q * 4);
                wsm[q * 4 + 0][c] = v.x; wsm[q * 4 + 1][c] = v.y;
                wsm[q * 4 + 2][c] = v.z; wsm[q * 4 + 3][c] = v.w;
            }
        }
        __syncthreads();

        #pragma unroll
        for (int k = 0; k < KC; k++) {
            float4 w4 = *(const float4*)&wsm[k][col0];
            float4 xa = *(const float4*)&xs[k][ty * 16 + 0];
            float4 xb = *(const float4*)&xs[k][ty * 16 + 4];
            float4 xc = *(const float4*)&xs[k][ty * 16 + 8];
            float4 xd = *(const float4*)&xs[k][ty * 16 + 12];
            float xr[16] = {xa.x, xa.y, xa.z, xa.w, xb.x, xb.y, xb.z, xb.w,
                            xc.x, xc.y, xc.z, xc.w, xd.x, xd.y, xd.z, xd.w};
            float wr[4]  = {w4.x, w4.y, w4.z, w4.w};
            #pragma unroll
            for (int i = 0; i < 16; i++)
                #pragma unroll
                for (int j = 0; j < 4; j++)
                    acc[i][j] += xr[i] * wr[j];
        }
        __syncthreads();
    }

    #pragma unroll
    for (int i = 0; i < 16; i++) {
        int gr = row0g + ty * 16 + i;
        if (gr < n) {
            float4 v = make_float4(acc[i][0], acc[i][1], acc[i][2], acc[i][3]);
            *(float4*)&h[(size_t)gr * WIDTH + col0] = v;
        }
    }
}

// ---------------------------------------------------------------------------
// out[n][c] = b[c] + dinv[n]^2 * h[n][c]   (self-loop term; initializes out)
// ---------------------------------------------------------------------------
__global__ __launch_bounds__(256) void self_init(const float* __restrict__ h,
                                                 const float* __restrict__ dinv,
                                                 const float* __restrict__ b,
                                                 float* __restrict__ out) {
    int node = blockIdx.x;
    int c = threadIdx.x;
    float dv = dinv[node];
    out[(size_t)node * WIDTH + c] = b[c] + dv * dv * h[(size_t)node * WIDTH + c];
}

// ---------------------------------------------------------------------------
// edge scatter: out[dst] += dinv[src]*dinv[dst] * h[src]
// one block per edge, one thread per column; coalesced atomics.
// ---------------------------------------------------------------------------
__global__ __launch_bounds__(256) void edge_agg(const float* __restrict__ h,
                                                const float* __restrict__ dinv,
                                                const int* __restrict__ src,
                                                const int* __restrict__ dst,
                                                float* __restrict__ out) {
    int e = blockIdx.x;
    int c = threadIdx.x;
    int s = src[e];
    int d = dst[e];
    float nrm = dinv[s] * dinv[d];
    atomicAdd(&out[(size_t)d * WIDTH + c], nrm * h[(size_t)s * WIDTH + c]);
}

// ---------------------------------------------------------------------------
// in-place LayerNorm + ReLU over width=256, one block per node
// ---------------------------------------------------------------------------
__global__ __launch_bounds__(256) void ln_relu(float* __restrict__ out,
                                               const float* __restrict__ gamma,
                                               const float* __restrict__ beta) {
    int node = blockIdx.x;
    int t = threadIdx.x;
    float v = out[(size_t)node * WIDTH + t];
    float s = v, s2 = v * v;
    #pragma unroll
    for (int off = 32; off > 0; off >>= 1) {
        s  += __shfl_down(s, off, 64);
        s2 += __shfl_down(s2, off, 64);
    }
    __shared__ float red[8];
    int wid = t >> 6;
    if ((t & 63) == 0) { red[wid] = s; red[4 + wid] = s2; }
    __syncthreads();
    float S  = red[0] + red[1] + red[2] + red[3];
    float S2 = red[4] + red[5] + red[6] + red[7];
    float mu   = S * (1.0f / 256.0f);
    float var  = S2 * (1.0f / 256.0f) - mu * mu;
    float rstd = rsqrtf(var + LN_EPS);
    float y = (v - mu) * rstd * gamma[t] + beta[t];
    out[(size_t)node * WIDTH + t] = fmaxf(y, 0.0f);
}

// ---------------------------------------------------------------------------
extern "C" void kernel_launch(void* const* d_in, const int* in_sizes, int n_in,
                              void* d_out, int out_size, void* d_ws, size_t ws_size,
                              hipStream_t stream) {
    const float* x     = (const float*)d_in[0];
    const int*   ei    = (const int*)d_in[1];   // [2, E] flat: src then dst
    const float* W     = (const float*)d_in[2];
    const float* b     = (const float*)d_in[3];
    const float* gamma = (const float*)d_in[4];
    const float* beta  = (const float*)d_in[5];
    float* out = (float*)d_out;

    const int* src = ei;
    const int* dst = ei + N_EDGES;

    // workspace layout: dinv[50000] | h[50000*256]
    float* dinv = (float*)d_ws;
    float* h    = (float*)d_ws + 50176;  // 256B-aligned offset past dinv

    const int n = N_NODES, e = N_EDGES;

    deg_init <<<(n + 255) / 256, 256, 0, stream>>>(dinv, n);
    deg_count<<<(e + 255) / 256, 256, 0, stream>>>(dst, dinv, e);
    deg_rsqrt<<<(n + 255) / 256, 256, 0, stream>>>(dinv, n);

    gemm_xWt <<<(n + 63) / 64, 256, 0, stream>>>(x, W, h, n);

    self_init<<<n, 256, 0, stream>>>(h, dinv, b, out);
    edge_agg <<<e, 256, 0, stream>>>(h, dinv, src, dst, out);
    ln_relu  <<<n, 256, 0, stream>>>(out, gamma, beta);
}

// Round 2
// 332.467 us; speedup vs baseline: 1.6247x; 1.6247x over previous
//
#include <hip/hip_runtime.h>
#include <hip/hip_bf16.h>

#define N_NODES 50000
#define N_EDGES 312500
#define WIDTH   256
#define LN_EPS  1e-5f
#define NB_SCAN 196   // ceil(50000/256)

// ---------------------------------------------------------------------------
// CSR build: count -> 3-pass exclusive scan -> fill
// ---------------------------------------------------------------------------
__global__ void count_dst(const int* __restrict__ dst, int* __restrict__ counts, int e) {
    int i = blockIdx.x * blockDim.x + threadIdx.x;
    if (i < e) atomicAdd(&counts[dst[i]], 1);
}

// Pass A: per-block sums of counts
__global__ __launch_bounds__(256) void scan_pass_a(const int* __restrict__ counts,
                                                   int* __restrict__ block_sums, int n) {
    int t = threadIdx.x;
    int i = blockIdx.x * 256 + t;
    int v = (i < n) ? counts[i] : 0;
    // wave reduce
    #pragma unroll
    for (int off = 32; off > 0; off >>= 1) v += __shfl_down(v, off, 64);
    __shared__ int ws[4];
    if ((t & 63) == 0) ws[t >> 6] = v;
    __syncthreads();
    if (t == 0) block_sums[blockIdx.x] = ws[0] + ws[1] + ws[2] + ws[3];
}

// Pass B: single-block exclusive scan of block_sums (nb <= 256)
__global__ __launch_bounds__(256) void scan_pass_b(int* __restrict__ block_sums, int nb) {
    int t = threadIdx.x;
    int lane = t & 63, w = t >> 6;
    int v = (t < nb) ? block_sums[t] : 0;
    int inc = v;
    #pragma unroll
    for (int off = 1; off < 64; off <<= 1) {
        int u = __shfl_up(inc, off, 64);
        if (lane >= off) inc += u;
    }
    __shared__ int wsum[4];
    if (lane == 63) wsum[w] = inc;
    __syncthreads();
    int woff = 0;
    for (int k = 0; k < 4; k++) if (k < w) woff += wsum[k];
    if (t < nb) block_sums[t] = inc - v + woff;  // exclusive
}

// Pass C: final offsets; also cursor init (reuses counts array) and dinv
__global__ __launch_bounds__(256) void scan_pass_c(int* __restrict__ counts,   // in: counts, out: cursor
                                                   const int* __restrict__ block_sums,
                                                   int* __restrict__ offsets,
                                                   float* __restrict__ dinv, int n) {
    int t = threadIdx.x;
    int i = blockIdx.x * 256 + t;
    int lane = t & 63, w = t >> 6;
    int v = (i < n) ? counts[i] : 0;
    int inc = v;
    #pragma unroll
    for (int off = 1; off < 64; off <<= 1) {
        int u = __shfl_up(inc, off, 64);
        if (lane >= off) inc += u;
    }
    __shared__ int wsum[4];
    if (lane == 63) wsum[w] = inc;
    __syncthreads();
    int woff = 0;
    for (int k = 0; k < 4; k++) if (k < w) woff += wsum[k];
    int excl = block_sums[blockIdx.x] + inc - v + woff;
    if (i < n) {
        offsets[i] = excl;
        counts[i]  = excl;                       // cursor starts at offset
        dinv[i]    = rsqrtf((float)(v + 1));     // +1 self-loop
    }
    if (i == n - 1) offsets[n] = N_EDGES;        // total is static
}

__global__ void fill_csr(const int* __restrict__ src, const int* __restrict__ dst,
                         int* __restrict__ cursor, int* __restrict__ csr, int e) {
    int i = blockIdx.x * blockDim.x + threadIdx.x;
    if (i < e) {
        int pos = atomicAdd(&cursor[dst[i]], 1);
        csr[pos] = src[i];
    }
}

// ---------------------------------------------------------------------------
// GEMM: h[n][c] = sum_k x[n][k] * W[c][k]   (h = x @ W^T)
// block = 64 rows x 256 cols, thread = 16 rows x 4 cols, K chunked by 32.
// ---------------------------------------------------------------------------
#define KC 32
__global__ __launch_bounds__(256) void gemm_xWt(const float* __restrict__ x,
                                                const float* __restrict__ W,
                                                float* __restrict__ h, int n) {
    __shared__ float xs[KC][64];    // [k][r]
    __shared__ float wsm[KC][256];  // [k][c]
    const int t    = threadIdx.x;
    const int tx   = t & 63;
    const int ty   = t >> 6;
    const int col0 = tx * 4;
    const int row0g = blockIdx.x * 64;

    float acc[16][4];
    #pragma unroll
    for (int i = 0; i < 16; i++)
        #pragma unroll
        for (int j = 0; j < 4; j++) acc[i][j] = 0.0f;

    for (int k0 = 0; k0 < WIDTH; k0 += KC) {
        {
            int r  = t & 63;
            int kq = (t >> 6) * 8;
            int gr = row0g + r;
            if (gr < n) {
                const float* xp = x + (size_t)gr * WIDTH + k0 + kq;
                float4 v0 = *(const float4*)xp;
                float4 v1 = *(const float4*)(xp + 4);
                xs[kq + 0][r] = v0.x; xs[kq + 1][r] = v0.y;
                xs[kq + 2][r] = v0.z; xs[kq + 3][r] = v0.w;
                xs[kq + 4][r] = v1.x; xs[kq + 5][r] = v1.y;
                xs[kq + 6][r] = v1.z; xs[kq + 7][r] = v1.w;
            } else {
                #pragma unroll
                for (int j = 0; j < 8; j++) xs[kq + j][r] = 0.0f;
            }
        }
        {
            int c = t;
            const float* wp = W + (size_t)c * WIDTH + k0;
            #pragma unroll
            for (int q = 0; q < 8; q++) {
                float4 v = *(const float4*)(wp + q * 4);
                wsm[q * 4 + 0][c] = v.x; wsm[q * 4 + 1][c] = v.y;
                wsm[q * 4 + 2][c] = v.z; wsm[q * 4 + 3][c] = v.w;
            }
        }
        __syncthreads();

        #pragma unroll
        for (int k = 0; k < KC; k++) {
            float4 w4 = *(const float4*)&wsm[k][col0];
            float4 xa = *(const float4*)&xs[k][ty * 16 + 0];
            float4 xb = *(const float4*)&xs[k][ty * 16 + 4];
            float4 xc = *(const float4*)&xs[k][ty * 16 + 8];
            float4 xd = *(const float4*)&xs[k][ty * 16 + 12];
            float xr[16] = {xa.x, xa.y, xa.z, xa.w, xb.x, xb.y, xb.z, xb.w,
                            xc.x, xc.y, xc.z, xc.w, xd.x, xd.y, xd.z, xd.w};
            float wr[4]  = {w4.x, w4.y, w4.z, w4.w};
            #pragma unroll
            for (int i = 0; i < 16; i++)
                #pragma unroll
                for (int j = 0; j < 4; j++)
                    acc[i][j] += xr[i] * wr[j];
        }
        __syncthreads();
    }

    #pragma unroll
    for (int i = 0; i < 16; i++) {
        int gr = row0g + ty * 16 + i;
        if (gr < n) {
            float4 v = make_float4(acc[i][0], acc[i][1], acc[i][2], acc[i][3]);
            *(float4*)&h[(size_t)gr * WIDTH + col0] = v;
        }
    }
}

// ---------------------------------------------------------------------------
// Fused gather + self-loop + bias + LayerNorm + ReLU. One block per dst node.
// out[d] = LN( b + dinv[d]*( dinv[d]*h[d] + sum_{s in N(d)} dinv[s]*h[s] ) )
// ---------------------------------------------------------------------------
__global__ __launch_bounds__(256) void gather_ln(const float* __restrict__ h,
                                                 const float* __restrict__ dinv,
                                                 const int* __restrict__ offsets,
                                                 const int* __restrict__ csr,
                                                 const float* __restrict__ b,
                                                 const float* __restrict__ gamma,
                                                 const float* __restrict__ beta,
                                                 float* __restrict__ out) {
    int d = blockIdx.x;
    int t = threadIdx.x;
    int beg = offsets[d], end = offsets[d + 1];
    float dv = dinv[d];
    float acc = dv * h[(size_t)d * WIDTH + t];   // self-loop (x dv again at end)

    __shared__ int   sidx[256];
    __shared__ float sdv[256];
    for (int base = beg; base < end; base += 256) {
        int cnt = min(end - base, 256);
        if (t < cnt) {
            int s = csr[base + t];
            sidx[t] = s;
            sdv[t]  = dinv[s];
        }
        __syncthreads();
        for (int q = 0; q < cnt; q++) {
            int s = sidx[q];
            acc += sdv[q] * h[(size_t)s * WIDTH + t];
        }
        __syncthreads();
    }

    float v = b[t] + dv * acc;

    // LayerNorm + ReLU across the 256-wide row
    float s1 = v, s2 = v * v;
    #pragma unroll
    for (int off = 32; off > 0; off >>= 1) {
        s1 += __shfl_down(s1, off, 64);
        s2 += __shfl_down(s2, off, 64);
    }
    __shared__ float red[8];
    int wid = t >> 6;
    if ((t & 63) == 0) { red[wid] = s1; red[4 + wid] = s2; }
    __syncthreads();
    float S  = red[0] + red[1] + red[2] + red[3];
    float S2 = red[4] + red[5] + red[6] + red[7];
    float mu   = S * (1.0f / 256.0f);
    float var  = S2 * (1.0f / 256.0f) - mu * mu;
    float rstd = rsqrtf(var + LN_EPS);
    float y = (v - mu) * rstd * gamma[t] + beta[t];
    out[(size_t)d * WIDTH + t] = fmaxf(y, 0.0f);
}

// ---------------------------------------------------------------------------
extern "C" void kernel_launch(void* const* d_in, const int* in_sizes, int n_in,
                              void* d_out, int out_size, void* d_ws, size_t ws_size,
                              hipStream_t stream) {
    const float* x     = (const float*)d_in[0];
    const int*   ei    = (const int*)d_in[1];   // [2, E] flat: src then dst
    const float* W     = (const float*)d_in[2];
    const float* b     = (const float*)d_in[3];
    const float* gamma = (const float*)d_in[4];
    const float* beta  = (const float*)d_in[5];
    float* out = (float*)d_out;

    const int* src = ei;
    const int* dst = ei + N_EDGES;

    const int n = N_NODES, e = N_EDGES;

    // workspace layout (4-byte units)
    float* dinv       = (float*)d_ws;                       // [50048] padded
    float* h          = (float*)d_ws + 50048;               // [12.8M], 16B aligned
    int*   counts     = (int*)d_ws + 50048 + 12800000;      // [50000] -> becomes cursor
    int*   offsets    = counts + 50000;                     // [50001]
    int*   block_sums = offsets + 50432;                    // [256]
    int*   csr        = block_sums + 256;                   // [312500]

    hipMemsetAsync(counts, 0, n * sizeof(int), stream);

    count_dst  <<<(e + 255) / 256, 256, 0, stream>>>(dst, counts, e);
    scan_pass_a<<<NB_SCAN, 256, 0, stream>>>(counts, block_sums, n);
    scan_pass_b<<<1, 256, 0, stream>>>(block_sums, NB_SCAN);
    scan_pass_c<<<NB_SCAN, 256, 0, stream>>>(counts, block_sums, offsets, dinv, n);
    fill_csr   <<<(e + 255) / 256, 256, 0, stream>>>(src, dst, counts, csr, e);

    gemm_xWt   <<<(n + 63) / 64, 256, 0, stream>>>(x, W, h, n);

    gather_ln  <<<n, 256, 0, stream>>>(h, dinv, offsets, csr, b, gamma, beta, out);
}

// Round 3
// 256.096 us; speedup vs baseline: 2.1092x; 1.2982x over previous
//
#include <hip/hip_runtime.h>
#include <hip/hip_bf16.h>

#define N_NODES 50000
#define N_EDGES 312500
#define WIDTH   256
#define LN_EPS  1e-5f
#define NB_SCAN 196   // ceil(50000/256)

typedef __attribute__((ext_vector_type(8))) short bf16x8;
typedef __attribute__((ext_vector_type(4))) float f32x4;

// ---------------------------------------------------------------------------
// CSR build: count -> 3-pass exclusive scan -> fill
// ---------------------------------------------------------------------------
__global__ void count_dst(const int* __restrict__ dst, int* __restrict__ counts, int e) {
    int i = blockIdx.x * blockDim.x + threadIdx.x;
    if (i < e) atomicAdd(&counts[dst[i]], 1);
}

__global__ __launch_bounds__(256) void scan_pass_a(const int* __restrict__ counts,
                                                   int* __restrict__ block_sums, int n) {
    int t = threadIdx.x;
    int i = blockIdx.x * 256 + t;
    int v = (i < n) ? counts[i] : 0;
    #pragma unroll
    for (int off = 32; off > 0; off >>= 1) v += __shfl_down(v, off, 64);
    __shared__ int ws[4];
    if ((t & 63) == 0) ws[t >> 6] = v;
    __syncthreads();
    if (t == 0) block_sums[blockIdx.x] = ws[0] + ws[1] + ws[2] + ws[3];
}

__global__ __launch_bounds__(256) void scan_pass_b(int* __restrict__ block_sums, int nb) {
    int t = threadIdx.x;
    int lane = t & 63, w = t >> 6;
    int v = (t < nb) ? block_sums[t] : 0;
    int inc = v;
    #pragma unroll
    for (int off = 1; off < 64; off <<= 1) {
        int u = __shfl_up(inc, off, 64);
        if (lane >= off) inc += u;
    }
    __shared__ int wsum[4];
    if (lane == 63) wsum[w] = inc;
    __syncthreads();
    int woff = 0;
    for (int k = 0; k < 4; k++) if (k < w) woff += wsum[k];
    if (t < nb) block_sums[t] = inc - v + woff;  // exclusive
}

__global__ __launch_bounds__(256) void scan_pass_c(int* __restrict__ counts,   // in: counts, out: cursor
                                                   const int* __restrict__ block_sums,
                                                   int* __restrict__ offsets,
                                                   float* __restrict__ dinv, int n) {
    int t = threadIdx.x;
    int i = blockIdx.x * 256 + t;
    int lane = t & 63, w = t >> 6;
    int v = (i < n) ? counts[i] : 0;
    int inc = v;
    #pragma unroll
    for (int off = 1; off < 64; off <<= 1) {
        int u = __shfl_up(inc, off, 64);
        if (lane >= off) inc += u;
    }
    __shared__ int wsum[4];
    if (lane == 63) wsum[w] = inc;
    __syncthreads();
    int woff = 0;
    for (int k = 0; k < 4; k++) if (k < w) woff += wsum[k];
    int excl = block_sums[blockIdx.x] + inc - v + woff;
    if (i < n) {
        offsets[i] = excl;
        counts[i]  = excl;                       // cursor starts at offset
        dinv[i]    = rsqrtf((float)(v + 1));     // +1 self-loop
    }
    if (i == n - 1) offsets[n] = N_EDGES;
}

__global__ void fill_csr(const int* __restrict__ src, const int* __restrict__ dst,
                         int* __restrict__ cursor, int* __restrict__ csr, int e) {
    int i = blockIdx.x * blockDim.x + threadIdx.x;
    if (i < e) {
        int pos = atomicAdd(&cursor[dst[i]], 1);
        csr[pos] = src[i];
    }
}

// ---------------------------------------------------------------------------
// fp32 -> bf16 conversion: blocks [0,6250) convert x (12.8M), [6250,6282) W (64K)
// ---------------------------------------------------------------------------
__global__ __launch_bounds__(256) void conv_bf16(const float* __restrict__ x,
                                                 const float* __restrict__ W,
                                                 __hip_bfloat16* __restrict__ xb,
                                                 __hip_bfloat16* __restrict__ Wb) {
    int blk = blockIdx.x;
    const float* src;
    __hip_bfloat16* dst;
    size_t i;
    if (blk < 6250) { src = x; dst = xb; i = ((size_t)blk * 256 + threadIdx.x) * 8; }
    else            { src = W; dst = Wb; i = ((size_t)(blk - 6250) * 256 + threadIdx.x) * 8; }
    float4 v0 = *(const float4*)(src + i);
    float4 v1 = *(const float4*)(src + i + 4);
    union { __hip_bfloat16 h[8]; bf16x8 v; } u;
    u.h[0] = __float2bfloat16(v0.x); u.h[1] = __float2bfloat16(v0.y);
    u.h[2] = __float2bfloat16(v0.z); u.h[3] = __float2bfloat16(v0.w);
    u.h[4] = __float2bfloat16(v1.x); u.h[5] = __float2bfloat16(v1.y);
    u.h[6] = __float2bfloat16(v1.z); u.h[7] = __float2bfloat16(v1.w);
    *(bf16x8*)(dst + i) = u.v;
}

// ---------------------------------------------------------------------------
// MFMA GEMM: h[m][nc] = sum_k xb[m][k] * Wb[nc][k]  (bf16 in, fp32 acc, bf16 out)
// Block 256 thr = 4 waves (2x2), tile 128x128, BK=64, K=256.
// LDS rows padded to 72 shorts (144 B) -> b128 fragment reads <=2-way conflict.
// A-frag: A[m=lane&15][k=quad*8+j]; B-frag: B[n=lane&15][k=quad*8+j];
// C/D: col=lane&15, row=quad*4+reg   [per cdna_hip_programming.md §3, m89-verified]
// ---------------------------------------------------------------------------
__global__ __launch_bounds__(256) void gemm_mfma(const __hip_bfloat16* __restrict__ xb,
                                                 const __hip_bfloat16* __restrict__ Wb,
                                                 __hip_bfloat16* __restrict__ h) {
    __shared__ short As[128][72];
    __shared__ short Bs[128][72];
    const int t    = threadIdx.x;
    const int lane = t & 63;
    const int wv   = t >> 6;
    const int wm   = wv & 1;          // wave m-half
    const int wn   = wv >> 1;         // wave n-half
    const int lrow = lane & 15;
    const int quad = lane >> 4;
    const int mrow0 = blockIdx.x * 128;
    const int ncol0 = blockIdx.y * 128;

    f32x4 acc[4][4];
    #pragma unroll
    for (int i = 0; i < 4; i++)
        #pragma unroll
        for (int j = 0; j < 4; j++)
            #pragma unroll
            for (int r = 0; r < 4; r++) acc[i][j][r] = 0.0f;

    const int sr = t >> 3;            // 0..31  staging row within pass
    const int sg = t & 7;             // 0..7   16B group within 64-k chunk

    for (int kc = 0; kc < 4; kc++) {
        int k0 = kc * 64;
        if (kc) __syncthreads();
        #pragma unroll
        for (int p = 0; p < 4; p++) {
            int r  = p * 32 + sr;
            int gr = mrow0 + r;
            bf16x8 av = {0, 0, 0, 0, 0, 0, 0, 0};
            if (gr < N_NODES)
                av = *(const bf16x8*)(xb + (size_t)gr * WIDTH + k0 + sg * 8);
            *(bf16x8*)&As[r][sg * 8] = av;
            int gn = ncol0 + r;       // always < 256
            *(bf16x8*)&Bs[r][sg * 8] = *(const bf16x8*)(Wb + (size_t)gn * WIDTH + k0 + sg * 8);
        }
        __syncthreads();

        #pragma unroll
        for (int s = 0; s < 2; s++) {
            bf16x8 af[4], bfr[4];
            #pragma unroll
            for (int i = 0; i < 4; i++)
                af[i] = *(const bf16x8*)&As[wm * 64 + i * 16 + lrow][s * 32 + quad * 8];
            #pragma unroll
            for (int j = 0; j < 4; j++)
                bfr[j] = *(const bf16x8*)&Bs[wn * 64 + j * 16 + lrow][s * 32 + quad * 8];
            #pragma unroll
            for (int i = 0; i < 4; i++)
                #pragma unroll
                for (int j = 0; j < 4; j++)
                    acc[i][j] = __builtin_amdgcn_mfma_f32_16x16x32_bf16(
                        af[i], bfr[j], acc[i][j], 0, 0, 0);
        }
    }

    #pragma unroll
    for (int i = 0; i < 4; i++) {
        #pragma unroll
        for (int j = 0; j < 4; j++) {
            int col = ncol0 + wn * 64 + j * 16 + lrow;
            #pragma unroll
            for (int r = 0; r < 4; r++) {
                int gr = mrow0 + wm * 64 + i * 16 + quad * 4 + r;
                if (gr < N_NODES)
                    h[(size_t)gr * WIDTH + col] = __float2bfloat16(acc[i][j][r]);
            }
        }
    }
}

// ---------------------------------------------------------------------------
// Fused gather + self-loop + bias + LayerNorm + ReLU. One block per dst node.
// ---------------------------------------------------------------------------
__global__ __launch_bounds__(256) void gather_ln(const __hip_bfloat16* __restrict__ h,
                                                 const float* __restrict__ dinv,
                                                 const int* __restrict__ offsets,
                                                 const int* __restrict__ csr,
                                                 const float* __restrict__ b,
                                                 const float* __restrict__ gamma,
                                                 const float* __restrict__ beta,
                                                 float* __restrict__ out) {
    int d = blockIdx.x;
    int t = threadIdx.x;
    int beg = offsets[d], end = offsets[d + 1];
    float dv = dinv[d];
    float acc = dv * __bfloat162float(h[(size_t)d * WIDTH + t]);

    __shared__ int   sidx[256];
    __shared__ float sdv[256];
    for (int base = beg; base < end; base += 256) {
        int cnt = min(end - base, 256);
        if (t < cnt) {
            int s = csr[base + t];
            sidx[t] = s;
            sdv[t]  = dinv[s];
        }
        __syncthreads();
        for (int q = 0; q < cnt; q++) {
            int s = sidx[q];
            acc += sdv[q] * __bfloat162float(h[(size_t)s * WIDTH + t]);
        }
        __syncthreads();
    }

    float v = b[t] + dv * acc;

    float s1 = v, s2 = v * v;
    #pragma unroll
    for (int off = 32; off > 0; off >>= 1) {
        s1 += __shfl_down(s1, off, 64);
        s2 += __shfl_down(s2, off, 64);
    }
    __shared__ float red[8];
    int wid = t >> 6;
    if ((t & 63) == 0) { red[wid] = s1; red[4 + wid] = s2; }
    __syncthreads();
    float S  = red[0] + red[1] + red[2] + red[3];
    float S2 = red[4] + red[5] + red[6] + red[7];
    float mu   = S * (1.0f / 256.0f);
    float var  = S2 * (1.0f / 256.0f) - mu * mu;
    float rstd = rsqrtf(var + LN_EPS);
    float y = (v - mu) * rstd * gamma[t] + beta[t];
    out[(size_t)d * WIDTH + t] = fmaxf(y, 0.0f);
}

// ---------------------------------------------------------------------------
extern "C" void kernel_launch(void* const* d_in, const int* in_sizes, int n_in,
                              void* d_out, int out_size, void* d_ws, size_t ws_size,
                              hipStream_t stream) {
    const float* x     = (const float*)d_in[0];
    const int*   ei    = (const int*)d_in[1];   // [2, E] flat: src then dst
    const float* W     = (const float*)d_in[2];
    const float* b     = (const float*)d_in[3];
    const float* gamma = (const float*)d_in[4];
    const float* beta  = (const float*)d_in[5];
    float* out = (float*)d_out;

    const int* src = ei;
    const int* dst = ei + N_EDGES;

    const int n = N_NODES, e = N_EDGES;

    // workspace layout (4-byte word offsets):
    //   dinv   [0, 50048)
    //   xb     [50048, 6450048)          bf16 x, 12.8M elems
    //   h      [6450048, 12850048)       bf16 h, 12.8M elems
    //   counts [12850048, 12900048)      cursor; OVERLAID by Wb after fill_csr
    //   offsets[12900048, 12950052)
    //   bsums  [12950052, 12950308)
    //   csr    [12950308, 13262808)
    float* wsf = (float*)d_ws;
    float*          dinv       = wsf;
    __hip_bfloat16* xb         = (__hip_bfloat16*)(wsf + 50048);
    __hip_bfloat16* h          = (__hip_bfloat16*)(wsf + 6450048);
    int*            counts     = (int*)(wsf + 12850048);
    __hip_bfloat16* Wb         = (__hip_bfloat16*)(wsf + 12850048);  // overlays counts
    int*            offsets    = (int*)(wsf + 12900048);
    int*            block_sums = (int*)(wsf + 12950052);
    int*            csr        = (int*)(wsf + 12950308);

    hipMemsetAsync(counts, 0, n * sizeof(int), stream);

    count_dst  <<<(e + 255) / 256, 256, 0, stream>>>(dst, counts, e);
    scan_pass_a<<<NB_SCAN, 256, 0, stream>>>(counts, block_sums, n);
    scan_pass_b<<<1, 256, 0, stream>>>(block_sums, NB_SCAN);
    scan_pass_c<<<NB_SCAN, 256, 0, stream>>>(counts, block_sums, offsets, dinv, n);
    fill_csr   <<<(e + 255) / 256, 256, 0, stream>>>(src, dst, counts, csr, e);

    conv_bf16  <<<6250 + 32, 256, 0, stream>>>(x, W, xb, Wb);

    dim3 ggrid((N_NODES + 127) / 128, 2);
    gemm_mfma  <<<ggrid, 256, 0, stream>>>(xb, Wb, h);

    gather_ln  <<<n, 256, 0, stream>>>(h, dinv, offsets, csr, b, gamma, beta, out);
}

// Round 4
// 205.823 us; speedup vs baseline: 2.6244x; 1.2443x over previous
//
#include <hip/hip_runtime.h>
#include <hip/hip_bf16.h>

#define N_NODES 50000
#define N_EDGES 312500
#define WIDTH   256
#define LN_EPS  1e-5f
#define NB_SCAN 196   // ceil(50000/256)

typedef __attribute__((ext_vector_type(8))) short bf16x8;
typedef __attribute__((ext_vector_type(4))) float f32x4;

__device__ __forceinline__ float bf_lo(unsigned u) { return __uint_as_float(u << 16); }
__device__ __forceinline__ float bf_hi(unsigned u) { return __uint_as_float(u & 0xffff0000u); }

// ---------------------------------------------------------------------------
// CSR build: count -> 3-pass exclusive scan -> fill
// ---------------------------------------------------------------------------
__global__ void count_dst(const int* __restrict__ dst, int* __restrict__ counts, int e) {
    int i = blockIdx.x * blockDim.x + threadIdx.x;
    if (i < e) atomicAdd(&counts[dst[i]], 1);
}

__global__ __launch_bounds__(256) void scan_pass_a(const int* __restrict__ counts,
                                                   int* __restrict__ block_sums, int n) {
    int t = threadIdx.x;
    int i = blockIdx.x * 256 + t;
    int v = (i < n) ? counts[i] : 0;
    #pragma unroll
    for (int off = 32; off > 0; off >>= 1) v += __shfl_down(v, off, 64);
    __shared__ int ws[4];
    if ((t & 63) == 0) ws[t >> 6] = v;
    __syncthreads();
    if (t == 0) block_sums[blockIdx.x] = ws[0] + ws[1] + ws[2] + ws[3];
}

__global__ __launch_bounds__(256) void scan_pass_b(int* __restrict__ block_sums, int nb) {
    int t = threadIdx.x;
    int lane = t & 63, w = t >> 6;
    int v = (t < nb) ? block_sums[t] : 0;
    int inc = v;
    #pragma unroll
    for (int off = 1; off < 64; off <<= 1) {
        int u = __shfl_up(inc, off, 64);
        if (lane >= off) inc += u;
    }
    __shared__ int wsum[4];
    if (lane == 63) wsum[w] = inc;
    __syncthreads();
    int woff = 0;
    for (int k = 0; k < 4; k++) if (k < w) woff += wsum[k];
    if (t < nb) block_sums[t] = inc - v + woff;  // exclusive
}

__global__ __launch_bounds__(256) void scan_pass_c(int* __restrict__ counts,   // in: counts, out: cursor
                                                   const int* __restrict__ block_sums,
                                                   int* __restrict__ offsets,
                                                   float* __restrict__ dinv, int n) {
    int t = threadIdx.x;
    int i = blockIdx.x * 256 + t;
    int lane = t & 63, w = t >> 6;
    int v = (i < n) ? counts[i] : 0;
    int inc = v;
    #pragma unroll
    for (int off = 1; off < 64; off <<= 1) {
        int u = __shfl_up(inc, off, 64);
        if (lane >= off) inc += u;
    }
    __shared__ int wsum[4];
    if (lane == 63) wsum[w] = inc;
    __syncthreads();
    int woff = 0;
    for (int k = 0; k < 4; k++) if (k < w) woff += wsum[k];
    int excl = block_sums[blockIdx.x] + inc - v + woff;
    if (i < n) {
        offsets[i] = excl;
        counts[i]  = excl;                       // cursor starts at offset
        dinv[i]    = rsqrtf((float)(v + 1));     // +1 self-loop
    }
    if (i == n - 1) offsets[n] = N_EDGES;
}

__global__ void fill_csr(const int* __restrict__ src, const int* __restrict__ dst,
                         int* __restrict__ cursor, int* __restrict__ csr, int e) {
    int i = blockIdx.x * blockDim.x + threadIdx.x;
    if (i < e) {
        int pos = atomicAdd(&cursor[dst[i]], 1);
        csr[pos] = src[i];
    }
}

// ---------------------------------------------------------------------------
// fp32 -> bf16 conversion: blocks [0,6250) convert x (12.8M), [6250,6282) W (64K)
// ---------------------------------------------------------------------------
__global__ __launch_bounds__(256) void conv_bf16(const float* __restrict__ x,
                                                 const float* __restrict__ W,
                                                 __hip_bfloat16* __restrict__ xb,
                                                 __hip_bfloat16* __restrict__ Wb) {
    int blk = blockIdx.x;
    const float* src;
    __hip_bfloat16* dst;
    size_t i;
    if (blk < 6250) { src = x; dst = xb; i = ((size_t)blk * 256 + threadIdx.x) * 8; }
    else            { src = W; dst = Wb; i = ((size_t)(blk - 6250) * 256 + threadIdx.x) * 8; }
    float4 v0 = *(const float4*)(src + i);
    float4 v1 = *(const float4*)(src + i + 4);
    union { __hip_bfloat16 h[8]; bf16x8 v; } u;
    u.h[0] = __float2bfloat16(v0.x); u.h[1] = __float2bfloat16(v0.y);
    u.h[2] = __float2bfloat16(v0.z); u.h[3] = __float2bfloat16(v0.w);
    u.h[4] = __float2bfloat16(v1.x); u.h[5] = __float2bfloat16(v1.y);
    u.h[6] = __float2bfloat16(v1.z); u.h[7] = __float2bfloat16(v1.w);
    *(bf16x8*)(dst + i) = u.v;
}

// ---------------------------------------------------------------------------
// MFMA GEMM: h[m][nc] = sum_k xb[m][k] * Wb[nc][k]  (bf16 in, fp32 acc, bf16 out)
// Block 256 thr = 4 waves (2x2), tile 128x128, BK=64, K=256.
// ---------------------------------------------------------------------------
__global__ __launch_bounds__(256) void gemm_mfma(const __hip_bfloat16* __restrict__ xb,
                                                 const __hip_bfloat16* __restrict__ Wb,
                                                 __hip_bfloat16* __restrict__ h) {
    __shared__ short As[128][72];
    __shared__ short Bs[128][72];
    const int t    = threadIdx.x;
    const int lane = t & 63;
    const int wv   = t >> 6;
    const int wm   = wv & 1;
    const int wn   = wv >> 1;
    const int lrow = lane & 15;
    const int quad = lane >> 4;
    const int mrow0 = blockIdx.x * 128;
    const int ncol0 = blockIdx.y * 128;

    f32x4 acc[4][4];
    #pragma unroll
    for (int i = 0; i < 4; i++)
        #pragma unroll
        for (int j = 0; j < 4; j++)
            #pragma unroll
            for (int r = 0; r < 4; r++) acc[i][j][r] = 0.0f;

    const int sr = t >> 3;
    const int sg = t & 7;

    for (int kc = 0; kc < 4; kc++) {
        int k0 = kc * 64;
        if (kc) __syncthreads();
        #pragma unroll
        for (int p = 0; p < 4; p++) {
            int r  = p * 32 + sr;
            int gr = mrow0 + r;
            bf16x8 av = {0, 0, 0, 0, 0, 0, 0, 0};
            if (gr < N_NODES)
                av = *(const bf16x8*)(xb + (size_t)gr * WIDTH + k0 + sg * 8);
            *(bf16x8*)&As[r][sg * 8] = av;
            int gn = ncol0 + r;
            *(bf16x8*)&Bs[r][sg * 8] = *(const bf16x8*)(Wb + (size_t)gn * WIDTH + k0 + sg * 8);
        }
        __syncthreads();

        #pragma unroll
        for (int s = 0; s < 2; s++) {
            bf16x8 af[4], bfr[4];
            #pragma unroll
            for (int i = 0; i < 4; i++)
                af[i] = *(const bf16x8*)&As[wm * 64 + i * 16 + lrow][s * 32 + quad * 8];
            #pragma unroll
            for (int j = 0; j < 4; j++)
                bfr[j] = *(const bf16x8*)&Bs[wn * 64 + j * 16 + lrow][s * 32 + quad * 8];
            #pragma unroll
            for (int i = 0; i < 4; i++)
                #pragma unroll
                for (int j = 0; j < 4; j++)
                    acc[i][j] = __builtin_amdgcn_mfma_f32_16x16x32_bf16(
                        af[i], bfr[j], acc[i][j], 0, 0, 0);
        }
    }

    #pragma unroll
    for (int i = 0; i < 4; i++) {
        #pragma unroll
        for (int j = 0; j < 4; j++) {
            int col = ncol0 + wn * 64 + j * 16 + lrow;
            #pragma unroll
            for (int r = 0; r < 4; r++) {
                int gr = mrow0 + wm * 64 + i * 16 + quad * 4 + r;
                if (gr < N_NODES)
                    h[(size_t)gr * WIDTH + col] = __float2bfloat16(acc[i][j][r]);
            }
        }
    }
}

// ---------------------------------------------------------------------------
// Fused gather + self-loop + bias + LayerNorm + ReLU.
// ONE WAVE per dst node; lane l owns cols 4l..4l+3 (uint2 = 4 bf16 per row read).
// Edge idx batch-loaded into lanes, broadcast via shfl. No LDS, no syncthreads.
// ---------------------------------------------------------------------------
__global__ __launch_bounds__(256) void gather_ln(const __hip_bfloat16* __restrict__ h,
                                                 const float* __restrict__ dinv,
                                                 const int* __restrict__ offsets,
                                                 const int* __restrict__ csr,
                                                 const float* __restrict__ b,
                                                 const float* __restrict__ gamma,
                                                 const float* __restrict__ beta,
                                                 float* __restrict__ out) {
    const int lane = threadIdx.x & 63;
    const int d    = blockIdx.x * 4 + (threadIdx.x >> 6);
    if (d >= N_NODES) return;

    const uint2* hrows = (const uint2*)h;        // 64 uint2 per row
    int beg = offsets[d], end = offsets[d + 1];
    float dv = dinv[d];

    // self-loop row (scaled by dv; whole sum scaled by dv again later)
    uint2 hv = hrows[(size_t)d * 64 + lane];
    float a0 = dv * bf_lo(hv.x), a1 = dv * bf_hi(hv.x);
    float a2 = dv * bf_lo(hv.y), a3 = dv * bf_hi(hv.y);

    for (int base = beg; base < end; base += 64) {
        int cnt = min(end - base, 64);
        int   s  = 0;
        float sv = 0.0f;
        if (lane < cnt) {
            s  = csr[base + lane];
            sv = dinv[s];
        }
        for (int q = 0; q < cnt; q++) {
            int   sq  = __shfl(s, q, 64);
            float svq = __shfl(sv, q, 64);
            uint2 rv  = hrows[(size_t)sq * 64 + lane];
            a0 += svq * bf_lo(rv.x);
            a1 += svq * bf_hi(rv.x);
            a2 += svq * bf_lo(rv.y);
            a3 += svq * bf_hi(rv.y);
        }
    }

    float4 bv = *(const float4*)(b + lane * 4);
    float v0 = bv.x + dv * a0;
    float v1 = bv.y + dv * a1;
    float v2 = bv.z + dv * a2;
    float v3 = bv.w + dv * a3;

    float s1 = v0 + v1 + v2 + v3;
    float s2 = v0 * v0 + v1 * v1 + v2 * v2 + v3 * v3;
    #pragma unroll
    for (int off = 32; off > 0; off >>= 1) {
        s1 += __shfl_xor(s1, off, 64);
        s2 += __shfl_xor(s2, off, 64);
    }
    float mu   = s1 * (1.0f / 256.0f);
    float var  = s2 * (1.0f / 256.0f) - mu * mu;
    float rstd = rsqrtf(var + LN_EPS);

    float4 gv = *(const float4*)(gamma + lane * 4);
    float4 bt = *(const float4*)(beta + lane * 4);
    float4 y;
    y.x = fmaxf((v0 - mu) * rstd * gv.x + bt.x, 0.0f);
    y.y = fmaxf((v1 - mu) * rstd * gv.y + bt.y, 0.0f);
    y.z = fmaxf((v2 - mu) * rstd * gv.z + bt.z, 0.0f);
    y.w = fmaxf((v3 - mu) * rstd * gv.w + bt.w, 0.0f);
    *(float4*)(out + (size_t)d * WIDTH + lane * 4) = y;
}

// ---------------------------------------------------------------------------
extern "C" void kernel_launch(void* const* d_in, const int* in_sizes, int n_in,
                              void* d_out, int out_size, void* d_ws, size_t ws_size,
                              hipStream_t stream) {
    const float* x     = (const float*)d_in[0];
    const int*   ei    = (const int*)d_in[1];   // [2, E] flat: src then dst
    const float* W     = (const float*)d_in[2];
    const float* b     = (const float*)d_in[3];
    const float* gamma = (const float*)d_in[4];
    const float* beta  = (const float*)d_in[5];
    float* out = (float*)d_out;

    const int* src = ei;
    const int* dst = ei + N_EDGES;

    const int n = N_NODES, e = N_EDGES;

    // workspace layout (4-byte word offsets):
    //   dinv   [0, 50048)
    //   xb     [50048, 6450048)          bf16 x, 12.8M elems
    //   h      [6450048, 12850048)       bf16 h, 12.8M elems
    //   counts [12850048, 12900048)      cursor; OVERLAID by Wb after fill_csr
    //   offsets[12900048, 12950052)
    //   bsums  [12950052, 12950308)
    //   csr    [12950308, 13262808)
    float* wsf = (float*)d_ws;
    float*          dinv       = wsf;
    __hip_bfloat16* xb         = (__hip_bfloat16*)(wsf + 50048);
    __hip_bfloat16* h          = (__hip_bfloat16*)(wsf + 6450048);
    int*            counts     = (int*)(wsf + 12850048);
    __hip_bfloat16* Wb         = (__hip_bfloat16*)(wsf + 12850048);  // overlays counts
    int*            offsets    = (int*)(wsf + 12900048);
    int*            block_sums = (int*)(wsf + 12950052);
    int*            csr        = (int*)(wsf + 12950308);

    hipMemsetAsync(counts, 0, n * sizeof(int), stream);

    count_dst  <<<(e + 255) / 256, 256, 0, stream>>>(dst, counts, e);
    scan_pass_a<<<NB_SCAN, 256, 0, stream>>>(counts, block_sums, n);
    scan_pass_b<<<1, 256, 0, stream>>>(block_sums, NB_SCAN);
    scan_pass_c<<<NB_SCAN, 256, 0, stream>>>(counts, block_sums, offsets, dinv, n);
    fill_csr   <<<(e + 255) / 256, 256, 0, stream>>>(src, dst, counts, csr, e);

    conv_bf16  <<<6250 + 32, 256, 0, stream>>>(x, W, xb, Wb);

    dim3 ggrid((N_NODES + 127) / 128, 2);
    gemm_mfma  <<<ggrid, 256, 0, stream>>>(xb, Wb, h);

    gather_ln  <<<(n + 3) / 4, 256, 0, stream>>>(h, dinv, offsets, csr, b, gamma, beta, out);
}